// Round 5
// baseline (4142.490 us; speedup 1.0000x reference)
//
#include <hip/hip_runtime.h>

namespace {

using u16 = unsigned short;
typedef short s16x8 __attribute__((ext_vector_type(8)));
typedef float f32x4 __attribute__((ext_vector_type(4)));
typedef u16 u16x4 __attribute__((ext_vector_type(4)));

constexpr int kH  = 768;
constexpr int kW  = 10;
constexpr int kL  = 10;
constexpr int kB  = 512;
constexpr int kG  = 3072;      // 4*H
constexpr int kTB = 5120;      // W*B
constexpr int kFC1_SPLIT = 12; // fc1 split-K chunks (Ksub = 640)

// ---- bf16 helpers (RNE) ----
__device__ __forceinline__ u16 f2bf(float x) {
  unsigned u = __float_as_uint(x);
  unsigned r = (u + 0x7fffu + ((u >> 16) & 1u)) >> 16;
  return (u16)r;
}
__device__ __forceinline__ float bf2f(u16 h) {
  return __uint_as_float(((unsigned)h) << 16);
}

// ---- async global->LDS, 16B/lane, LDS dst wave-uniform base + lane*16 ----
__device__ __forceinline__ void gl2lds(const void* g, void* l) {
  __builtin_amdgcn_global_load_lds(
      (const __attribute__((address_space(1))) void*)g,
      (__attribute__((address_space(3))) void*)l, 16, 0, 0);
}

__device__ __forceinline__ f32x4 mfma16(s16x8 a, s16x8 b, f32x4 c) {
  return __builtin_amdgcn_mfma_f32_16x16x32_bf16(a, b, c, 0, 0, 0);
}

__device__ __forceinline__ float sigm(float x) { return 1.f / (1.f + __expf(-x)); }

// ---------------- fp32 -> bf16 hi/lo split (4 elems/thread) ----------------
__device__ __forceinline__ void split_store(const float4 v, u16* hi, u16* lo, int idx) {
  u16x4 h, l;
  h[0] = f2bf(v.x); l[0] = f2bf(v.x - bf2f(h[0]));
  h[1] = f2bf(v.y); l[1] = f2bf(v.y - bf2f(h[1]));
  h[2] = f2bf(v.z); l[2] = f2bf(v.z - bf2f(h[2]));
  h[3] = f2bf(v.w); l[3] = f2bf(v.w - bf2f(h[3]));
  reinterpret_cast<u16x4*>(hi)[idx] = h;
  reinterpret_cast<u16x4*>(lo)[idx] = l;
}

__global__ __launch_bounds__(256) void split4(const float* __restrict__ in,
                                              u16* __restrict__ hi,
                                              u16* __restrict__ lo) {
  int idx = blockIdx.x * 256 + threadIdx.x;
  split_store(reinterpret_cast<const float4*>(in)[idx], hi, lo, idx);
}

// ---- paired splitter: wih + whh in one dispatch (each kG*kH floats) ----
__global__ __launch_bounds__(256) void split2(const float* __restrict__ a,
                                              const float* __restrict__ b,
                                              u16* __restrict__ ahi, u16* __restrict__ alo,
                                              u16* __restrict__ bhi, u16* __restrict__ blo) {
  int idx = blockIdx.x * 256 + threadIdx.x;
  constexpr int half = kG * kH / 4;
  const float* in = a;
  u16 *hi = ahi, *lo = alo;
  if (idx >= half) { in = b; hi = bhi; lo = blo; idx -= half; }
  split_store(reinterpret_cast<const float4*>(in)[idx], hi, lo, idx);
}

// ---------------- transpose (B,W,H)->(W,B,H) + split ----------------
__global__ __launch_bounds__(256) void transpose_split(const float* __restrict__ src,
                                                       u16* __restrict__ hi,
                                                       u16* __restrict__ lo) {
  int idx = blockIdx.x * 256 + threadIdx.x;   // float4 units, 5120*192 total
  int h4 = idx % 192;
  int rest = idx / 192;
  int b = rest % kB;
  int t = rest / kB;
  float4 v = reinterpret_cast<const float4*>(src)[((size_t)b * kW + t) * 192 + h4];
  split_store(v, hi, lo, (int)(((size_t)t * kB + b) * 192 + h4));
}

// ---------------- pack (W,B,H)->(B,W*H), bf16 pairs ----------------
__global__ __launch_bounds__(256) void pack_sp(const u16* __restrict__ Yhi,
                                               const u16* __restrict__ Ylo,
                                               u16* __restrict__ Xhi,
                                               u16* __restrict__ Xlo) {
  int idx = blockIdx.x * 256 + threadIdx.x;   // uint4 units (8 u16)
  int h8 = idx % 96;
  int rest = idx / 96;
  int w = rest % kW;
  int b = rest / kW;
  size_t s = ((size_t)w * kB + b) * 96 + h8;
  size_t d = ((size_t)b * kW + w) * 96 + h8;
  reinterpret_cast<uint4*>(Xhi)[d] = reinterpret_cast<const uint4*>(Yhi)[s];
  reinterpret_cast<uint4*>(Xlo)[d] = reinterpret_cast<const uint4*>(Ylo)[s];
}

// ======== bf16x3 GEMM, 2-phase dbuf: C[M,N] = A[M,K] @ W[N,K]^T ========
// BN=128, BK=32; 4 waves. EPI: 0 fp32+bias1; 1 split hi/lo+bias1;
// 2 fp32+bias1+bias2; 3 fp32 split-K partials (blockIdx.z plane, no bias).
template <int BM, int EPI>
__global__ __launch_bounds__(256) void gemm_bf3(
    const u16* __restrict__ Ahi, const u16* __restrict__ Alo,
    const u16* __restrict__ Bhi, const u16* __restrict__ Blo,
    const float* __restrict__ bias1, const float* __restrict__ bias2,
    float* __restrict__ Cf, u16* __restrict__ Chi, u16* __restrict__ Clo,
    int M, int N, int K, int Ksub) {
  constexpr int MR = BM / 64;      // m-fragment repeats per wave
  constexpr int WR = BM / 4;       // rows per wave
  __shared__ u16 sAh[2][BM * 32], sAl[2][BM * 32];
  __shared__ u16 sBh[2][128 * 32], sBl[2][128 * 32];
  const int tid = threadIdx.x;
  const int wid = tid >> 6;
  const int lane = tid & 63;
  const int bm = blockIdx.y * BM;
  const int bn = blockIdx.x * 128;
  const int kbeg = blockIdx.z * Ksub;

  f32x4 acc[MR][8];
#pragma unroll
  for (int m = 0; m < MR; ++m)
#pragma unroll
    for (int n = 0; n < 8; ++n) acc[m][n] = {0.f, 0.f, 0.f, 0.f};

  const int ko = (lane >> 4) * 8;          // k-chunk for fragment reads
  const int cl = lane & 15;
  const int srow = lane >> 2;              // staging: row within 16-group
  const int scol = (lane & 3) * 8;         // staging: k offset (u16 units)

  auto STAGE = [&](int bi, int k0) {
#pragma unroll
    for (int c = 0; c < MR; ++c) {
      int g16 = (wid * MR + c) * 16;
      size_t goff = (size_t)(bm + g16 + srow) * K + k0 + scol;
      gl2lds(Ahi + goff, &sAh[bi][g16 * 32]);
      gl2lds(Alo + goff, &sAl[bi][g16 * 32]);
    }
#pragma unroll
    for (int c = 0; c < 2; ++c) {
      int g16 = (wid * 2 + c) * 16;
      size_t goff = (size_t)(bn + g16 + srow) * K + k0 + scol;
      gl2lds(Bhi + goff, &sBh[bi][g16 * 32]);
      gl2lds(Blo + goff, &sBl[bi][g16 * 32]);
    }
  };

  auto COMPUTE = [&](int bi) {
    s16x8 ah[MR], al[MR];
#pragma unroll
    for (int m = 0; m < MR; ++m) {
      int row = wid * WR + m * 16 + cl;
      ah[m] = *reinterpret_cast<const s16x8*>(&sAh[bi][row * 32 + ko]);
      al[m] = *reinterpret_cast<const s16x8*>(&sAl[bi][row * 32 + ko]);
    }
#pragma unroll
    for (int n = 0; n < 8; ++n) {
      int row = n * 16 + cl;
      s16x8 bh = *reinterpret_cast<const s16x8*>(&sBh[bi][row * 32 + ko]);
      s16x8 bl = *reinterpret_cast<const s16x8*>(&sBl[bi][row * 32 + ko]);
#pragma unroll
      for (int m = 0; m < MR; ++m) acc[m][n] = mfma16(ah[m], bh, acc[m][n]);
#pragma unroll
      for (int m = 0; m < MR; ++m) acc[m][n] = mfma16(ah[m], bl, acc[m][n]);
#pragma unroll
      for (int m = 0; m < MR; ++m) acc[m][n] = mfma16(al[m], bh, acc[m][n]);
    }
  };

  const int NT = Ksub / 32;
  STAGE(0, kbeg);
  asm volatile("s_waitcnt vmcnt(0)" ::: "memory");
  __syncthreads();
  int cur = 0;
  for (int t = 0; t < NT - 1; ++t) {
    STAGE(cur ^ 1, kbeg + (t + 1) * 32);   // issue next tile BEFORE compute
    COMPUTE(cur);                          // ds_read + MFMA hide load latency
    asm volatile("s_waitcnt vmcnt(0)" ::: "memory");
    __syncthreads();
    cur ^= 1;
  }
  COMPUTE(cur);

  const int rq = (lane >> 4) * 4;
#pragma unroll
  for (int m = 0; m < MR; ++m) {
#pragma unroll
    for (int n = 0; n < 8; ++n) {
      int col = bn + n * 16 + cl;
      float badd = (EPI != 3 && bias1) ? bias1[col] : 0.f;
      if (EPI == 2) badd += bias2[col];
#pragma unroll
      for (int q = 0; q < 4; ++q) {
        int row = bm + wid * WR + m * 16 + rq + q;
        float v = acc[m][n][q] + badd;
        if (EPI == 1) {
          size_t off = (size_t)row * N + col;
          u16 h = f2bf(v);
          Chi[off] = h;
          Clo[off] = f2bf(v - bf2f(h));
        } else if (EPI == 3) {
          size_t off = ((size_t)blockIdx.z * M + row) * N + col;
          Cf[off] = v;
        } else {
          Cf[(size_t)row * N + col] = v;
        }
      }
    }
  }
}

// ---- fc1 partial reduce: out = bias + sum_z part[z] ----
__global__ __launch_bounds__(256) void fc1_reduce(const float* __restrict__ part,
                                                  const float* __restrict__ bias,
                                                  float* __restrict__ out) {
  int idx = blockIdx.x * 256 + threadIdx.x;   // 512*768
  float s = bias[idx % kH];
#pragma unroll
  for (int z = 0; z < kFC1_SPLIT; ++z) s += part[(size_t)z * kB * kH + idx];
  out[idx] = s;
}

// ======== fused recurrent step (2-phase dbuf) ========
// g = h_{t-1} @ whh^T + gx[t]; gates; h,c out. BM=64 batch rows,
// 32 units x 4 gates = 128 cols. grid = (24, 8).
__global__ __launch_bounds__(256) void lstm_step(
    const u16* __restrict__ Hhi, const u16* __restrict__ Hlo,
    const u16* __restrict__ Whi, const u16* __restrict__ Wlo,
    const float* __restrict__ gxt,
    float* __restrict__ cbuf,
    u16* __restrict__ Ohi, u16* __restrict__ Olo) {
  __shared__ u16 sAh[2][64 * 32], sAl[2][64 * 32];
  __shared__ u16 sBh[2][128 * 32], sBl[2][128 * 32];
  const int tid = threadIdx.x;
  const int wid = tid >> 6;
  const int lane = tid & 63;
  const int u0 = blockIdx.x * 32;
  const int bm = blockIdx.y * 64;

  f32x4 acc[8];
#pragma unroll
  for (int n = 0; n < 8; ++n) acc[n] = {0.f, 0.f, 0.f, 0.f};

  const int ko = (lane >> 4) * 8;
  const int cl = lane & 15;
  const int srow = lane >> 2;
  const int scol = (lane & 3) * 8;

  auto STAGE = [&](int bi, int k0) {
    {  // A: 64 rows of H
      int g16 = wid * 16;
      size_t goff = (size_t)(bm + g16 + srow) * kH + k0 + scol;
      gl2lds(Hhi + goff, &sAh[bi][g16 * 32]);
      gl2lds(Hlo + goff, &sAl[bi][g16 * 32]);
    }
#pragma unroll
    for (int c = 0; c < 2; ++c) {  // B: 128 rows = 4 gate slabs x 32 units
      int g16 = (wid * 2 + c) * 16;
      int slab = g16 >> 5;
      int jb = g16 & 31;
      size_t goff = (size_t)(slab * kH + u0 + jb + srow) * kH + k0 + scol;
      gl2lds(Whi + goff, &sBh[bi][g16 * 32]);
      gl2lds(Wlo + goff, &sBl[bi][g16 * 32]);
    }
  };

  auto COMPUTE = [&](int bi) {
    int arow = wid * 16 + cl;
    s16x8 ah = *reinterpret_cast<const s16x8*>(&sAh[bi][arow * 32 + ko]);
    s16x8 al = *reinterpret_cast<const s16x8*>(&sAl[bi][arow * 32 + ko]);
#pragma unroll
    for (int n = 0; n < 8; ++n) {
      int row = n * 16 + cl;
      s16x8 bh = *reinterpret_cast<const s16x8*>(&sBh[bi][row * 32 + ko]);
      s16x8 bl = *reinterpret_cast<const s16x8*>(&sBl[bi][row * 32 + ko]);
      acc[n] = mfma16(ah, bh, acc[n]);
      acc[n] = mfma16(ah, bl, acc[n]);
      acc[n] = mfma16(al, bh, acc[n]);
    }
  };

  constexpr int NT = kH / 32;   // 24
  STAGE(0, 0);
  asm volatile("s_waitcnt vmcnt(0)" ::: "memory");
  __syncthreads();
  int cur = 0;
  for (int t = 0; t < NT - 1; ++t) {
    STAGE(cur ^ 1, (t + 1) * 32);
    COMPUTE(cur);
    asm volatile("s_waitcnt vmcnt(0)" ::: "memory");
    __syncthreads();
    cur ^= 1;
  }
  COMPUTE(cur);

  // epilogue: frag n -> gate n>>1, unit-half n&1. Per lane: all 4 gates of unit u.
  const int rq = (lane >> 4) * 4;
#pragma unroll
  for (int h = 0; h < 2; ++h) {
    int u = u0 + h * 16 + cl;
#pragma unroll
    for (int q = 0; q < 4; ++q) {
      int r = bm + wid * 16 + rq + q;
      size_t gb = (size_t)r * kG;
      float gi = acc[0 + h][q] + gxt[gb + u];
      float gf = acc[2 + h][q] + gxt[gb + kH + u];
      float gg = acc[4 + h][q] + gxt[gb + 2 * kH + u];
      float go = acc[6 + h][q] + gxt[gb + 3 * kH + u];
      float i_ = sigm(gi), f_ = sigm(gf), g_ = tanhf(gg), o_ = sigm(go);
      size_t co = (size_t)r * kH + u;
      float cn = fmaf(f_, cbuf[co], i_ * g_);
      cbuf[co] = cn;
      float hv = o_ * tanhf(cn);
      u16 hh = f2bf(hv);
      Ohi[co] = hh;
      Olo[co] = f2bf(hv - bf2f(hh));
    }
  }
}

// ---------------- t=0 gates (h0 = 0, c0 = 0) ----------------
__global__ __launch_bounds__(256) void lstm_t0(const float* __restrict__ gxt,
                                               float* __restrict__ cbuf,
                                               u16* __restrict__ Ohi,
                                               u16* __restrict__ Olo) {
  int idx = blockIdx.x * 256 + threadIdx.x;   // 512*768
  int b = idx / kH, u = idx % kH;
  size_t base = (size_t)b * kG;
  float gi = gxt[base + u];
  float gg = gxt[base + 2 * kH + u];
  float go = gxt[base + 3 * kH + u];
  float i_ = sigm(gi), g_ = tanhf(gg), o_ = sigm(go);
  float cn = i_ * g_;
  cbuf[idx] = cn;
  float hv = o_ * tanhf(cn);
  u16 hh = f2bf(hv);
  Ohi[idx] = hh;
  Olo[idx] = f2bf(hv - bf2f(hh));
}

}  // namespace

extern "C" void kernel_launch(void* const* d_in, const int* in_sizes, int n_in,
                              void* d_out, int out_size, void* d_ws, size_t ws_size,
                              hipStream_t stream) {
  const float* xpos  = (const float*)d_in[0];
  const float* fc0_w = (const float*)d_in[1];
  const float* fc0_b = (const float*)d_in[2];
  const float* w_ih  = (const float*)d_in[3];
  const float* w_hh  = (const float*)d_in[4];
  const float* b_ih  = (const float*)d_in[5];
  const float* b_hh  = (const float*)d_in[6];
  const float* fc1_w = (const float*)d_in[7];
  const float* fc1_b = (const float*)d_in[8];
  float* out = (float*)d_out;

  // ---- workspace (101,449,728 B total; proven available in rounds 3/4) ----
  // gx region [0, 62.9MB) aliases (each only live when gx dead or per order):
  //   Xt hi/lo [0, 15.7MB) ; fc1w split [16.8MB, 40.4MB) ;
  //   fc1 partials [40.4MB, 59.2MB)
  char* W = (char*)d_ws;
  float* gx      = (float*)W;                     // 5120*3072 f32
  u16* Xthi      = (u16*)W;                       // 5120*768
  u16* Xtlo      = Xthi + (size_t)kTB * kH;
  u16* fc1whi    = (u16*)(W + 16777216);          // 768*7680
  u16* fc1wlo    = fc1whi + (size_t)kH * kH * kW;
  float* fc1part = (float*)(W + 40370176);        // 12 * 512*768 f32
  u16* Yhi       = (u16*)(W + 62914560);          // 10*512*768
  u16* Ylo       = Yhi + (size_t)kTB * kH;
  float* cbuf    = (float*)(W + 78643200);        // 512*768
  u16* wihhi     = (u16*)(W + 80216064);          // 3072*768
  u16* wihlo     = wihhi + (size_t)kG * kH;
  u16* whhhi     = (u16*)(W + 89653248);
  u16* whhlo     = whhhi + (size_t)kG * kH;
  u16* fc0whi    = (u16*)(W + 99090432);          // 768*768
  u16* fc0wlo    = fc0whi + (size_t)kH * kH;

  dim3 blk(256);

  transpose_split<<<3840, blk, 0, stream>>>(xpos, Xthi, Xtlo);
  split4<<<576, blk, 0, stream>>>(fc0_w, fc0whi, fc0wlo);

  // fc0: Y = Xt @ fc0_w^T + b   (5120 x 768 x 768), split output
  gemm_bf3<128, 1><<<dim3(6, 40), blk, 0, stream>>>(
      Xthi, Xtlo, fc0whi, fc0wlo, fc0_b, nullptr, nullptr, Yhi, Ylo,
      kTB, kH, kH, kH);

  for (int l = 0; l < kL; ++l) {
    split2<<<4608, blk, 0, stream>>>(w_ih + (size_t)l * kG * kH,
                                     w_hh + (size_t)l * kG * kH,
                                     wihhi, wihlo, whhhi, whhlo);

    // gx = Y @ wih^T + b_ih + b_hh   (5120 x 3072 x 768)
    gemm_bf3<128, 2><<<dim3(24, 40), blk, 0, stream>>>(
        Yhi, Ylo, wihhi, wihlo, b_ih + (size_t)l * kG, b_hh + (size_t)l * kG,
        gx, nullptr, nullptr, kTB, kG, kH, kH);

    lstm_t0<<<1536, blk, 0, stream>>>(gx, cbuf, Yhi, Ylo);

    for (int t = 1; t < kW; ++t) {
      lstm_step<<<dim3(24, 8), blk, 0, stream>>>(
          Yhi + (size_t)(t - 1) * kB * kH, Ylo + (size_t)(t - 1) * kB * kH,
          whhhi, whhlo, gx + (size_t)t * kB * kG, cbuf,
          Yhi + (size_t)t * kB * kH, Ylo + (size_t)t * kB * kH);
    }
  }

  // fc1: split weight, pack xx, split-K GEMM into partials, reduce (+bias)
  split4<<<5760, blk, 0, stream>>>(fc1_w, fc1whi, fc1wlo);
  pack_sp<<<1920, blk, 0, stream>>>(Yhi, Ylo, Xthi, Xtlo);
  gemm_bf3<64, 3><<<dim3(6, 8, kFC1_SPLIT), blk, 0, stream>>>(
      Xthi, Xtlo, fc1whi, fc1wlo, nullptr, nullptr, fc1part, nullptr, nullptr,
      kB, kH, kW * kH, kW * kH / kFC1_SPLIT);
  fc1_reduce<<<1536, blk, 0, stream>>>(fc1part, fc1_b, out);
}

// Round 7
// 3789.279 us; speedup vs baseline: 1.0932x; 1.0932x over previous
//
#include <hip/hip_runtime.h>

namespace {

using u16 = unsigned short;
typedef short s16x8 __attribute__((ext_vector_type(8)));
typedef float f32x4 __attribute__((ext_vector_type(4)));
typedef u16 u16x4 __attribute__((ext_vector_type(4)));

constexpr int kH  = 768;
constexpr int kW  = 10;
constexpr int kL  = 10;
constexpr int kB  = 512;
constexpr int kG  = 3072;      // 4*H
constexpr int kTB = 5120;      // W*B
constexpr int kFC1_SPLIT = 12; // fc1 split-K chunks (Ksub = 640)

// ---- bf16 helpers (RNE) ----
__device__ __forceinline__ u16 f2bf(float x) {
  unsigned u = __float_as_uint(x);
  unsigned r = (u + 0x7fffu + ((u >> 16) & 1u)) >> 16;
  return (u16)r;
}
__device__ __forceinline__ float bf2f(u16 h) {
  return __uint_as_float(((unsigned)h) << 16);
}

// ---- async global->LDS, 16B/lane, LDS dst wave-uniform base + lane*16 ----
__device__ __forceinline__ void gl2lds(const void* g, void* l) {
  __builtin_amdgcn_global_load_lds(
      (const __attribute__((address_space(1))) void*)g,
      (__attribute__((address_space(3))) void*)l, 16, 0, 0);
}

__device__ __forceinline__ f32x4 mfma16(s16x8 a, s16x8 b, f32x4 c) {
  return __builtin_amdgcn_mfma_f32_16x16x32_bf16(a, b, c, 0, 0, 0);
}

__device__ __forceinline__ float sigm(float x) { return 1.f / (1.f + __expf(-x)); }

// ---- LDS tile swizzle (T2 via pre-swizzled source, rule #21) ----
// Tile = 16 rows x 32 u16 (64B/row). Chunk c (16B) of row r stored at
// chunk c ^ ((r>>1)&3). 16 lanes reading same k-chunk across 16 rows then
// occupy each 128B bank line exactly 2x -> 2-way (free, m136).
__device__ __forceinline__ int swz_u16(int row, int kc) {
  return row * 32 + ((kc ^ ((row >> 1) & 3)) << 3);
}

// ---------------- fp32 -> bf16 hi/lo split (4 elems/thread) ----------------
__device__ __forceinline__ void split_store(const float4 v, u16* hi, u16* lo, int idx) {
  u16x4 h, l;
  h[0] = f2bf(v.x); l[0] = f2bf(v.x - bf2f(h[0]));
  h[1] = f2bf(v.y); l[1] = f2bf(v.y - bf2f(h[1]));
  h[2] = f2bf(v.z); l[2] = f2bf(v.z - bf2f(h[2]));
  h[3] = f2bf(v.w); l[3] = f2bf(v.w - bf2f(h[3]));
  reinterpret_cast<u16x4*>(hi)[idx] = h;
  reinterpret_cast<u16x4*>(lo)[idx] = l;
}

__global__ __launch_bounds__(256) void split4(const float* __restrict__ in,
                                              u16* __restrict__ hi,
                                              u16* __restrict__ lo) {
  int idx = blockIdx.x * 256 + threadIdx.x;
  split_store(reinterpret_cast<const float4*>(in)[idx], hi, lo, idx);
}

// ---- paired splitter: wih + whh in one dispatch (each kG*kH floats) ----
__global__ __launch_bounds__(256) void split2(const float* __restrict__ a,
                                              const float* __restrict__ b,
                                              u16* __restrict__ ahi, u16* __restrict__ alo,
                                              u16* __restrict__ bhi, u16* __restrict__ blo) {
  int idx = blockIdx.x * 256 + threadIdx.x;
  constexpr int half = kG * kH / 4;
  const float* in = a;
  u16 *hi = ahi, *lo = alo;
  if (idx >= half) { in = b; hi = bhi; lo = blo; idx -= half; }
  split_store(reinterpret_cast<const float4*>(in)[idx], hi, lo, idx);
}

// ---------------- transpose (B,W,H)->(W,B,H) + split ----------------
__global__ __launch_bounds__(256) void transpose_split(const float* __restrict__ src,
                                                       u16* __restrict__ hi,
                                                       u16* __restrict__ lo) {
  int idx = blockIdx.x * 256 + threadIdx.x;   // float4 units, 5120*192 total
  int h4 = idx % 192;
  int rest = idx / 192;
  int b = rest % kB;
  int t = rest / kB;
  float4 v = reinterpret_cast<const float4*>(src)[((size_t)b * kW + t) * 192 + h4];
  split_store(v, hi, lo, (int)(((size_t)t * kB + b) * 192 + h4));
}

// ---------------- pack (W,B,H)->(B,W*H), bf16 pairs ----------------
__global__ __launch_bounds__(256) void pack_sp(const u16* __restrict__ Yhi,
                                               const u16* __restrict__ Ylo,
                                               u16* __restrict__ Xhi,
                                               u16* __restrict__ Xlo) {
  int idx = blockIdx.x * 256 + threadIdx.x;   // uint4 units (8 u16)
  int h8 = idx % 96;
  int rest = idx / 96;
  int w = rest % kW;
  int b = rest / kW;
  size_t s = ((size_t)w * kB + b) * 96 + h8;
  size_t d = ((size_t)b * kW + w) * 96 + h8;
  reinterpret_cast<uint4*>(Xhi)[d] = reinterpret_cast<const uint4*>(Yhi)[s];
  reinterpret_cast<uint4*>(Xlo)[d] = reinterpret_cast<const uint4*>(Ylo)[s];
}

// ======== bf16x3 GEMM, 2-phase dbuf + swizzled LDS ========
// C[M,N] = A[M,K] @ W[N,K]^T. BN=128, BK=32; 4 waves.
// EPI: 0 fp32+bias1; 1 split hi/lo+bias1; 2 fp32+bias1+bias2;
// 3 fp32 split-K partials (blockIdx.z plane, no bias).
template <int BM, int EPI>
__global__ __launch_bounds__(256) void gemm_bf3(
    const u16* __restrict__ Ahi, const u16* __restrict__ Alo,
    const u16* __restrict__ Bhi, const u16* __restrict__ Blo,
    const float* __restrict__ bias1, const float* __restrict__ bias2,
    float* __restrict__ Cf, u16* __restrict__ Chi, u16* __restrict__ Clo,
    int M, int N, int K, int Ksub) {
  constexpr int MR = BM / 64;      // m-fragment repeats per wave
  constexpr int WR = BM / 4;       // rows per wave
  __shared__ u16 sAh[2][BM * 32], sAl[2][BM * 32];
  __shared__ u16 sBh[2][128 * 32], sBl[2][128 * 32];
  const int tid = threadIdx.x;
  const int wid = tid >> 6;
  const int lane = tid & 63;
  const int bm = blockIdx.y * BM;
  const int bn = blockIdx.x * 128;
  const int kbeg = blockIdx.z * Ksub;

  f32x4 acc[MR][8];
#pragma unroll
  for (int m = 0; m < MR; ++m)
#pragma unroll
    for (int n = 0; n < 8; ++n) acc[m][n] = {0.f, 0.f, 0.f, 0.f};

  const int kc = lane >> 4;                // k-chunk (0..3) for fragment reads
  const int cl = lane & 15;
  const int srow = lane >> 2;              // staging: row within 16-group
  // pre-swizzled source chunk so data lands at the swizzled LDS slot
  const int scol = (((lane & 3) ^ ((srow >> 1) & 3)) << 3);

  auto STAGE = [&](int bi, int k0) {
#pragma unroll
    for (int c = 0; c < MR; ++c) {
      int g16 = (wid * MR + c) * 16;
      size_t goff = (size_t)(bm + g16 + srow) * K + k0 + scol;
      gl2lds(Ahi + goff, &sAh[bi][g16 * 32]);
      gl2lds(Alo + goff, &sAl[bi][g16 * 32]);
    }
#pragma unroll
    for (int c = 0; c < 2; ++c) {
      int g16 = (wid * 2 + c) * 16;
      size_t goff = (size_t)(bn + g16 + srow) * K + k0 + scol;
      gl2lds(Bhi + goff, &sBh[bi][g16 * 32]);
      gl2lds(Blo + goff, &sBl[bi][g16 * 32]);
    }
  };

  auto COMPUTE = [&](int bi) {
    s16x8 ah[MR], al[MR];
#pragma unroll
    for (int m = 0; m < MR; ++m) {
      int row = wid * WR + m * 16 + cl;
      ah[m] = *reinterpret_cast<const s16x8*>(&sAh[bi][swz_u16(row, kc)]);
      al[m] = *reinterpret_cast<const s16x8*>(&sAl[bi][swz_u16(row, kc)]);
    }
#pragma unroll
    for (int n = 0; n < 8; ++n) {
      int row = n * 16 + cl;
      s16x8 bh = *reinterpret_cast<const s16x8*>(&sBh[bi][swz_u16(row, kc)]);
      s16x8 bl = *reinterpret_cast<const s16x8*>(&sBl[bi][swz_u16(row, kc)]);
#pragma unroll
      for (int m = 0; m < MR; ++m) acc[m][n] = mfma16(ah[m], bh, acc[m][n]);
#pragma unroll
      for (int m = 0; m < MR; ++m) acc[m][n] = mfma16(ah[m], bl, acc[m][n]);
#pragma unroll
      for (int m = 0; m < MR; ++m) acc[m][n] = mfma16(al[m], bh, acc[m][n]);
    }
  };

  const int NT = Ksub / 32;
  STAGE(0, kbeg);
  asm volatile("s_waitcnt vmcnt(0)" ::: "memory");
  __syncthreads();
  int cur = 0;
  for (int t = 0; t < NT - 1; ++t) {
    STAGE(cur ^ 1, kbeg + (t + 1) * 32);   // issue next tile BEFORE compute
    COMPUTE(cur);                          // ds_read + MFMA hide load latency
    asm volatile("s_waitcnt vmcnt(0)" ::: "memory");
    __syncthreads();
    cur ^= 1;
  }
  COMPUTE(cur);

  const int rq = (lane >> 4) * 4;
#pragma unroll
  for (int m = 0; m < MR; ++m) {
#pragma unroll
    for (int n = 0; n < 8; ++n) {
      int col = bn + n * 16 + cl;
      float badd = (EPI != 3 && bias1) ? bias1[col] : 0.f;
      if (EPI == 2) badd += bias2[col];
#pragma unroll
      for (int q = 0; q < 4; ++q) {
        int row = bm + wid * WR + m * 16 + rq + q;
        float v = acc[m][n][q] + badd;
        if (EPI == 1) {
          size_t off = (size_t)row * N + col;
          u16 h = f2bf(v);
          Chi[off] = h;
          Clo[off] = f2bf(v - bf2f(h));
        } else if (EPI == 3) {
          size_t off = ((size_t)blockIdx.z * M + row) * N + col;
          Cf[off] = v;
        } else {
          Cf[(size_t)row * N + col] = v;
        }
      }
    }
  }
}

// ---- fc1 partial reduce: out = bias + sum_z part[z] ----
__global__ __launch_bounds__(256) void fc1_reduce(const float* __restrict__ part,
                                                  const float* __restrict__ bias,
                                                  float* __restrict__ out) {
  int idx = blockIdx.x * 256 + threadIdx.x;   // 512*768
  float s = bias[idx % kH];
#pragma unroll
  for (int z = 0; z < kFC1_SPLIT; ++z) s += part[(size_t)z * kB * kH + idx];
  out[idx] = s;
}

// ======== fused recurrent step — round-4 structure (REVERTED: the 2-phase
// dbuf port measured ~33us/step vs ~14.6us for this version) ========
// g = h_{t-1} @ whh^T + gx[t]; gates; h,c out. BM=64 batch rows,
// 32 units x 4 gates = 128 cols. grid = (24, 8).
__global__ __launch_bounds__(256) void lstm_step(
    const u16* __restrict__ Hhi, const u16* __restrict__ Hlo,
    const u16* __restrict__ Whi, const u16* __restrict__ Wlo,
    const float* __restrict__ gxt,
    float* __restrict__ cbuf,
    u16* __restrict__ Ohi, u16* __restrict__ Olo) {
  __shared__ u16 sAh[64 * 32], sAl[64 * 32], sBh[128 * 32], sBl[128 * 32];
  const int tid = threadIdx.x;
  const int wid = tid >> 6;
  const int lane = tid & 63;
  const int u0 = blockIdx.x * 32;
  const int bm = blockIdx.y * 64;

  f32x4 acc[8];
#pragma unroll
  for (int n = 0; n < 8; ++n) acc[n] = {0.f, 0.f, 0.f, 0.f};

  const int ko = (lane >> 4) * 8;
  const int cl = lane & 15;

  for (int k0 = 0; k0 < kH; k0 += 32) {
    {  // A: 64 rows of H
      int g16 = wid * 16;
      size_t goff = (size_t)(bm + g16 + (lane >> 2)) * kH + k0 + (lane & 3) * 8;
      gl2lds(Hhi + goff, &sAh[g16 * 32]);
      gl2lds(Hlo + goff, &sAl[g16 * 32]);
    }
#pragma unroll
    for (int c = 0; c < 2; ++c) {  // B: 128 rows = 4 gate slabs x 32 units
      int g16 = (wid * 2 + c) * 16;
      int slab = g16 >> 5;
      int jb = g16 & 31;
      size_t goff = (size_t)(slab * kH + u0 + jb + (lane >> 2)) * kH + k0 + (lane & 3) * 8;
      gl2lds(Whi + goff, &sBh[g16 * 32]);
      gl2lds(Wlo + goff, &sBl[g16 * 32]);
    }
    __syncthreads();

    int arow = wid * 16 + cl;
    s16x8 ah = *reinterpret_cast<const s16x8*>(&sAh[arow * 32 + ko]);
    s16x8 al = *reinterpret_cast<const s16x8*>(&sAl[arow * 32 + ko]);
#pragma unroll
    for (int n = 0; n < 8; ++n) {
      int row = n * 16 + cl;
      s16x8 bh = *reinterpret_cast<const s16x8*>(&sBh[row * 32 + ko]);
      s16x8 bl = *reinterpret_cast<const s16x8*>(&sBl[row * 32 + ko]);
      acc[n] = mfma16(ah, bh, acc[n]);
      acc[n] = mfma16(ah, bl, acc[n]);
      acc[n] = mfma16(al, bh, acc[n]);
    }
    __syncthreads();
  }

  // epilogue: frag n -> gate n>>1, unit-half n&1. Per lane: all 4 gates of unit u.
  const int rq = (lane >> 4) * 4;
#pragma unroll
  for (int h = 0; h < 2; ++h) {
    int u = u0 + h * 16 + cl;
#pragma unroll
    for (int q = 0; q < 4; ++q) {
      int r = bm + wid * 16 + rq + q;
      size_t gb = (size_t)r * kG;
      float gi = acc[0 + h][q] + gxt[gb + u];
      float gf = acc[2 + h][q] + gxt[gb + kH + u];
      float gg = acc[4 + h][q] + gxt[gb + 2 * kH + u];
      float go = acc[6 + h][q] + gxt[gb + 3 * kH + u];
      float i_ = sigm(gi), f_ = sigm(gf), g_ = tanhf(gg), o_ = sigm(go);
      size_t co = (size_t)r * kH + u;
      float cn = fmaf(f_, cbuf[co], i_ * g_);
      cbuf[co] = cn;
      float hv = o_ * tanhf(cn);
      u16 hh = f2bf(hv);
      Ohi[co] = hh;
      Olo[co] = f2bf(hv - bf2f(hh));
    }
  }
}

// ---------------- t=0 gates (h0 = 0, c0 = 0) ----------------
__global__ __launch_bounds__(256) void lstm_t0(const float* __restrict__ gxt,
                                               float* __restrict__ cbuf,
                                               u16* __restrict__ Ohi,
                                               u16* __restrict__ Olo) {
  int idx = blockIdx.x * 256 + threadIdx.x;   // 512*768
  int b = idx / kH, u = idx % kH;
  size_t base = (size_t)b * kG;
  float gi = gxt[base + u];
  float gg = gxt[base + 2 * kH + u];
  float go = gxt[base + 3 * kH + u];
  float i_ = sigm(gi), g_ = tanhf(gg), o_ = sigm(go);
  float cn = i_ * g_;
  cbuf[idx] = cn;
  float hv = o_ * tanhf(cn);
  u16 hh = f2bf(hv);
  Ohi[idx] = hh;
  Olo[idx] = f2bf(hv - bf2f(hh));
}

}  // namespace

extern "C" void kernel_launch(void* const* d_in, const int* in_sizes, int n_in,
                              void* d_out, int out_size, void* d_ws, size_t ws_size,
                              hipStream_t stream) {
  const float* xpos  = (const float*)d_in[0];
  const float* fc0_w = (const float*)d_in[1];
  const float* fc0_b = (const float*)d_in[2];
  const float* w_ih  = (const float*)d_in[3];
  const float* w_hh  = (const float*)d_in[4];
  const float* b_ih  = (const float*)d_in[5];
  const float* b_hh  = (const float*)d_in[6];
  const float* fc1_w = (const float*)d_in[7];
  const float* fc1_b = (const float*)d_in[8];
  float* out = (float*)d_out;

  // ---- workspace (101,449,728 B total; proven available) ----
  // gx region [0, 62.9MB) aliases: Xt hi/lo [0, 15.7MB); fc1w split
  // [16.8MB, 40.4MB); fc1 partials [40.4MB, 59.2MB)
  char* W = (char*)d_ws;
  float* gx      = (float*)W;                     // 5120*3072 f32
  u16* Xthi      = (u16*)W;                       // 5120*768
  u16* Xtlo      = Xthi + (size_t)kTB * kH;
  u16* fc1whi    = (u16*)(W + 16777216);          // 768*7680
  u16* fc1wlo    = fc1whi + (size_t)kH * kH * kW;
  float* fc1part = (float*)(W + 40370176);        // 12 * 512*768 f32
  u16* Yhi       = (u16*)(W + 62914560);          // 10*512*768
  u16* Ylo       = Yhi + (size_t)kTB * kH;
  float* cbuf    = (float*)(W + 78643200);        // 512*768
  u16* wihhi     = (u16*)(W + 80216064);          // 3072*768
  u16* wihlo     = wihhi + (size_t)kG * kH;
  u16* whhhi     = (u16*)(W + 89653248);
  u16* whhlo     = whhhi + (size_t)kG * kH;
  u16* fc0whi    = (u16*)(W + 99090432);          // 768*768
  u16* fc0wlo    = fc0whi + (size_t)kH * kH;

  dim3 blk(256);

  transpose_split<<<3840, blk, 0, stream>>>(xpos, Xthi, Xtlo);
  split4<<<576, blk, 0, stream>>>(fc0_w, fc0whi, fc0wlo);

  // fc0: Y = Xt @ fc0_w^T + b   (5120 x 768 x 768), split output
  gemm_bf3<128, 1><<<dim3(6, 40), blk, 0, stream>>>(
      Xthi, Xtlo, fc0whi, fc0wlo, fc0_b, nullptr, nullptr, Yhi, Ylo,
      kTB, kH, kH, kH);

  for (int l = 0; l < kL; ++l) {
    split2<<<4608, blk, 0, stream>>>(w_ih + (size_t)l * kG * kH,
                                     w_hh + (size_t)l * kG * kH,
                                     wihhi, wihlo, whhhi, whhlo);

    // gx = Y @ wih^T + b_ih + b_hh   (5120 x 3072 x 768)
    gemm_bf3<128, 2><<<dim3(24, 40), blk, 0, stream>>>(
        Yhi, Ylo, wihhi, wihlo, b_ih + (size_t)l * kG, b_hh + (size_t)l * kG,
        gx, nullptr, nullptr, kTB, kG, kH, kH);

    lstm_t0<<<1536, blk, 0, stream>>>(gx, cbuf, Yhi, Ylo);

    for (int t = 1; t < kW; ++t) {
      lstm_step<<<dim3(24, 8), blk, 0, stream>>>(
          Yhi + (size_t)(t - 1) * kB * kH, Ylo + (size_t)(t - 1) * kB * kH,
          whhhi, whhlo, gx + (size_t)t * kB * kG, cbuf,
          Yhi + (size_t)t * kB * kH, Ylo + (size_t)t * kB * kH);
    }
  }

  // fc1: split weight, pack xx, split-K GEMM into partials, reduce (+bias)
  split4<<<5760, blk, 0, stream>>>(fc1_w, fc1whi, fc1wlo);
  pack_sp<<<1920, blk, 0, stream>>>(Yhi, Ylo, Xthi, Xtlo);
  gemm_bf3<64, 3><<<dim3(6, 8, kFC1_SPLIT), blk, 0, stream>>>(
      Xthi, Xtlo, fc1whi, fc1wlo, nullptr, nullptr, fc1part, nullptr, nullptr,
      kB, kH, kW * kH, kW * kH / kFC1_SPLIT);
  fc1_reduce<<<1536, blk, 0, stream>>>(fc1part, fc1_b, out);
}

// Round 9
// 3603.788 us; speedup vs baseline: 1.1495x; 1.0515x over previous
//
#include <hip/hip_runtime.h>

namespace {

using u16 = unsigned short;
typedef short s16x8 __attribute__((ext_vector_type(8)));
typedef float f32x4 __attribute__((ext_vector_type(4)));
typedef u16 u16x4 __attribute__((ext_vector_type(4)));

constexpr int kH  = 768;
constexpr int kW  = 10;
constexpr int kL  = 10;
constexpr int kB  = 512;
constexpr int kG  = 3072;      // 4*H
constexpr int kTB = 5120;      // W*B
constexpr int kFC1_SPLIT = 12; // fc1 split-K chunks (Ksub = 640)

// ---- bf16 helpers (RNE) ----
__device__ __forceinline__ u16 f2bf(float x) {
  unsigned u = __float_as_uint(x);
  unsigned r = (u + 0x7fffu + ((u >> 16) & 1u)) >> 16;
  return (u16)r;
}
__device__ __forceinline__ float bf2f(u16 h) {
  return __uint_as_float(((unsigned)h) << 16);
}

// ---- async global->LDS, 16B/lane, LDS dst wave-uniform base + lane*16 ----
__device__ __forceinline__ void gl2lds(const void* g, void* l) {
  __builtin_amdgcn_global_load_lds(
      (const __attribute__((address_space(1))) void*)g,
      (__attribute__((address_space(3))) void*)l, 16, 0, 0);
}

__device__ __forceinline__ f32x4 mfma16(s16x8 a, s16x8 b, f32x4 c) {
  return __builtin_amdgcn_mfma_f32_16x16x32_bf16(a, b, c, 0, 0, 0);
}

__device__ __forceinline__ float sigm(float x) { return 1.f / (1.f + __expf(-x)); }

// ---- LDS tile swizzle (kept: SQ_LDS_BANK_CONFLICT 7.37M -> 0 measured) ----
__device__ __forceinline__ int swz_u16(int row, int kc) {
  return row * 32 + ((kc ^ ((row >> 1) & 3)) << 3);
}

// ---------------- fp32 -> bf16 hi/lo split (4 elems/thread) ----------------
__device__ __forceinline__ void split_store(const float4 v, u16* hi, u16* lo, int idx) {
  u16x4 h, l;
  h[0] = f2bf(v.x); l[0] = f2bf(v.x - bf2f(h[0]));
  h[1] = f2bf(v.y); l[1] = f2bf(v.y - bf2f(h[1]));
  h[2] = f2bf(v.z); l[2] = f2bf(v.z - bf2f(h[2]));
  h[3] = f2bf(v.w); l[3] = f2bf(v.w - bf2f(h[3]));
  reinterpret_cast<u16x4*>(hi)[idx] = h;
  reinterpret_cast<u16x4*>(lo)[idx] = l;
}

__global__ __launch_bounds__(256) void split4(const float* __restrict__ in,
                                              u16* __restrict__ hi,
                                              u16* __restrict__ lo) {
  int idx = blockIdx.x * 256 + threadIdx.x;
  split_store(reinterpret_cast<const float4*>(in)[idx], hi, lo, idx);
}

// ---- paired splitter: wih + whh in one dispatch (each kG*kH floats) ----
__global__ __launch_bounds__(256) void split2(const float* __restrict__ a,
                                              const float* __restrict__ b,
                                              u16* __restrict__ ahi, u16* __restrict__ alo,
                                              u16* __restrict__ bhi, u16* __restrict__ blo) {
  int idx = blockIdx.x * 256 + threadIdx.x;
  constexpr int half = kG * kH / 4;
  const float* in = a;
  u16 *hi = ahi, *lo = alo;
  if (idx >= half) { in = b; hi = bhi; lo = blo; idx -= half; }
  split_store(reinterpret_cast<const float4*>(in)[idx], hi, lo, idx);
}

// ---------------- transpose (B,W,H)->(W,B,H) + split ----------------
__global__ __launch_bounds__(256) void transpose_split(const float* __restrict__ src,
                                                       u16* __restrict__ hi,
                                                       u16* __restrict__ lo) {
  int idx = blockIdx.x * 256 + threadIdx.x;   // float4 units, 5120*192 total
  int h4 = idx % 192;
  int rest = idx / 192;
  int b = rest % kB;
  int t = rest / kB;
  float4 v = reinterpret_cast<const float4*>(src)[((size_t)b * kW + t) * 192 + h4];
  split_store(v, hi, lo, (int)(((size_t)t * kB + b) * 192 + h4));
}

// ---------------- pack (W,B,H)->(B,W*H), bf16 pairs ----------------
__global__ __launch_bounds__(256) void pack_sp(const u16* __restrict__ Yhi,
                                               const u16* __restrict__ Ylo,
                                               u16* __restrict__ Xhi,
                                               u16* __restrict__ Xlo) {
  int idx = blockIdx.x * 256 + threadIdx.x;   // uint4 units (8 u16)
  int h8 = idx % 96;
  int rest = idx / 96;
  int w = rest % kW;
  int b = rest / kW;
  size_t s = ((size_t)w * kB + b) * 96 + h8;
  size_t d = ((size_t)b * kW + w) * 96 + h8;
  reinterpret_cast<uint4*>(Xhi)[d] = reinterpret_cast<const uint4*>(Yhi)[s];
  reinterpret_cast<uint4*>(Xlo)[d] = reinterpret_cast<const uint4*>(Ylo)[s];
}

// ======== bf16x3 GEMM: dbuf + COUNTED vmcnt (T4) + raw barriers ========
// C[M,N] = A[M,K] @ W[N,K]^T. BN=128, BK=32; 4 waves.
// Loads for tile t+1 stay in flight across the barrier (vmcnt(N), never 0
// in-loop); raw s_barrier avoids __syncthreads' vmcnt(0) drain.
// EPI: 0 fp32+bias1; 1 split hi/lo+bias1; 2 fp32+bias1+bias2;
// 3 fp32 split-K partials (blockIdx.z plane, no bias).
template <int BM, int EPI>
__global__ __launch_bounds__(256) void gemm_bf3(
    const u16* __restrict__ Ahi, const u16* __restrict__ Alo,
    const u16* __restrict__ Bhi, const u16* __restrict__ Blo,
    const float* __restrict__ bias1, const float* __restrict__ bias2,
    float* __restrict__ Cf, u16* __restrict__ Chi, u16* __restrict__ Clo,
    int M, int N, int K, int Ksub) {
  constexpr int MR = BM / 64;      // m-fragment repeats per wave
  constexpr int WR = BM / 4;       // rows per wave
  __shared__ u16 sAh[2][BM * 32], sAl[2][BM * 32];
  __shared__ u16 sBh[2][128 * 32], sBl[2][128 * 32];
  const int tid = threadIdx.x;
  const int wid = tid >> 6;
  const int lane = tid & 63;
  const int bm = blockIdx.y * BM;
  const int bn = blockIdx.x * 128;
  const int kbeg = blockIdx.z * Ksub;

  f32x4 acc[MR][8];
#pragma unroll
  for (int m = 0; m < MR; ++m)
#pragma unroll
    for (int n = 0; n < 8; ++n) acc[m][n] = {0.f, 0.f, 0.f, 0.f};

  const int kc = lane >> 4;                // k-chunk (0..3) for fragment reads
  const int cl = lane & 15;
  const int srow = lane >> 2;              // staging: row within 16-group
  // pre-swizzled source chunk so data lands at the swizzled LDS slot
  const int scol = (((lane & 3) ^ ((srow >> 1) & 3)) << 3);

  auto STAGE = [&](int bi, int k0) {       // MR*2 + 4 loads per wave
#pragma unroll
    for (int c = 0; c < MR; ++c) {
      int g16 = (wid * MR + c) * 16;
      size_t goff = (size_t)(bm + g16 + srow) * K + k0 + scol;
      gl2lds(Ahi + goff, &sAh[bi][g16 * 32]);
      gl2lds(Alo + goff, &sAl[bi][g16 * 32]);
    }
#pragma unroll
    for (int c = 0; c < 2; ++c) {
      int g16 = (wid * 2 + c) * 16;
      size_t goff = (size_t)(bn + g16 + srow) * K + k0 + scol;
      gl2lds(Bhi + goff, &sBh[bi][g16 * 32]);
      gl2lds(Blo + goff, &sBl[bi][g16 * 32]);
    }
  };

  auto COMPUTE = [&](int bi) {
    s16x8 ah[MR], al[MR];
#pragma unroll
    for (int m = 0; m < MR; ++m) {
      int row = wid * WR + m * 16 + cl;
      ah[m] = *reinterpret_cast<const s16x8*>(&sAh[bi][swz_u16(row, kc)]);
      al[m] = *reinterpret_cast<const s16x8*>(&sAl[bi][swz_u16(row, kc)]);
    }
#pragma unroll
    for (int n = 0; n < 8; ++n) {
      int row = n * 16 + cl;
      s16x8 bh = *reinterpret_cast<const s16x8*>(&sBh[bi][swz_u16(row, kc)]);
      s16x8 bl = *reinterpret_cast<const s16x8*>(&sBl[bi][swz_u16(row, kc)]);
#pragma unroll
      for (int m = 0; m < MR; ++m) acc[m][n] = mfma16(ah[m], bh, acc[m][n]);
#pragma unroll
      for (int m = 0; m < MR; ++m) acc[m][n] = mfma16(ah[m], bl, acc[m][n]);
#pragma unroll
      for (int m = 0; m < MR; ++m) acc[m][n] = mfma16(al[m], bh, acc[m][n]);
    }
  };

  const int NT = Ksub / 32;
  STAGE(0, kbeg);
  int cur = 0;
  for (int t = 0; t < NT - 1; ++t) {
    STAGE(cur ^ 1, kbeg + (t + 1) * 32);   // 8 (BM=128) / 6 (BM=64) new loads
    // wait ONLY tile-t's loads (oldest); tile-t+1's stay in flight
    if constexpr (MR == 2) asm volatile("s_waitcnt vmcnt(8)" ::: "memory");
    else                   asm volatile("s_waitcnt vmcnt(6)" ::: "memory");
    __builtin_amdgcn_s_barrier();          // raw: no auto vmcnt(0) drain
    __builtin_amdgcn_sched_barrier(0);     // pin ds_reads after barrier
    COMPUTE(cur);
    __builtin_amdgcn_sched_barrier(0);     // pin ds_reads before barrier
    __builtin_amdgcn_s_barrier();          // all waves done reading buf cur
    cur ^= 1;
  }
  asm volatile("s_waitcnt vmcnt(0)" ::: "memory");
  __builtin_amdgcn_s_barrier();
  __builtin_amdgcn_sched_barrier(0);
  COMPUTE(cur);

  const int rq = (lane >> 4) * 4;
#pragma unroll
  for (int m = 0; m < MR; ++m) {
#pragma unroll
    for (int n = 0; n < 8; ++n) {
      int col = bn + n * 16 + cl;
      float badd = (EPI != 3 && bias1) ? bias1[col] : 0.f;
      if (EPI == 2) badd += bias2[col];
#pragma unroll
      for (int q = 0; q < 4; ++q) {
        int row = bm + wid * WR + m * 16 + rq + q;
        float v = acc[m][n][q] + badd;
        if (EPI == 1) {
          size_t off = (size_t)row * N + col;
          u16 h = f2bf(v);
          Chi[off] = h;
          Clo[off] = f2bf(v - bf2f(h));
        } else if (EPI == 3) {
          size_t off = ((size_t)blockIdx.z * M + row) * N + col;
          Cf[off] = v;
        } else {
          Cf[(size_t)row * N + col] = v;
        }
      }
    }
  }
}

// ---- fc1 partial reduce: out = bias + sum_z part[z] ----
__global__ __launch_bounds__(256) void fc1_reduce(const float* __restrict__ part,
                                                  const float* __restrict__ bias,
                                                  float* __restrict__ out) {
  int idx = blockIdx.x * 256 + threadIdx.x;   // 512*768
  float s = bias[idx % kH];
#pragma unroll
  for (int z = 0; z < kFC1_SPLIT; ++z) s += part[(size_t)z * kB * kH + idx];
  out[idx] = s;
}

// ======== fused recurrent step: dbuf + counted vmcnt (T4 port) ========
// Differs from the failed round-5 dbuf: vmcnt(6) BEFORE barrier-1 (loads in
// flight across barriers) + dual raw barriers, vs vmcnt(0)-after-compute.
// g = h_{t-1} @ whh^T + gx[t]; gates; h,c out. grid = (24, 8).
__global__ __launch_bounds__(256) void lstm_step(
    const u16* __restrict__ Hhi, const u16* __restrict__ Hlo,
    const u16* __restrict__ Whi, const u16* __restrict__ Wlo,
    const float* __restrict__ gxt,
    float* __restrict__ cbuf,
    u16* __restrict__ Ohi, u16* __restrict__ Olo) {
  __shared__ u16 sAh[2][64 * 32], sAl[2][64 * 32];
  __shared__ u16 sBh[2][128 * 32], sBl[2][128 * 32];
  const int tid = threadIdx.x;
  const int wid = tid >> 6;
  const int lane = tid & 63;
  const int u0 = blockIdx.x * 32;
  const int bm = blockIdx.y * 64;

  f32x4 acc[8];
#pragma unroll
  for (int n = 0; n < 8; ++n) acc[n] = {0.f, 0.f, 0.f, 0.f};

  const int kc = lane >> 4;
  const int cl = lane & 15;
  const int srow = lane >> 2;
  const int scol = (((lane & 3) ^ ((srow >> 1) & 3)) << 3);

  auto STAGE = [&](int bi, int k0) {       // 6 loads per wave
    {  // A: 64 rows of H
      int g16 = wid * 16;
      size_t goff = (size_t)(bm + g16 + srow) * kH + k0 + scol;
      gl2lds(Hhi + goff, &sAh[bi][g16 * 32]);
      gl2lds(Hlo + goff, &sAl[bi][g16 * 32]);
    }
#pragma unroll
    for (int c = 0; c < 2; ++c) {  // B: 128 rows = 4 gate slabs x 32 units
      int g16 = (wid * 2 + c) * 16;
      int slab = g16 >> 5;
      int jb = g16 & 31;
      size_t goff = (size_t)(slab * kH + u0 + jb + srow) * kH + k0 + scol;
      gl2lds(Whi + goff, &sBh[bi][g16 * 32]);
      gl2lds(Wlo + goff, &sBl[bi][g16 * 32]);
    }
  };

  auto COMPUTE = [&](int bi) {
    int arow = wid * 16 + cl;
    s16x8 ah = *reinterpret_cast<const s16x8*>(&sAh[bi][swz_u16(arow, kc)]);
    s16x8 al = *reinterpret_cast<const s16x8*>(&sAl[bi][swz_u16(arow, kc)]);
#pragma unroll
    for (int n = 0; n < 8; ++n) {
      int row = n * 16 + cl;
      s16x8 bh = *reinterpret_cast<const s16x8*>(&sBh[bi][swz_u16(row, kc)]);
      s16x8 bl = *reinterpret_cast<const s16x8*>(&sBl[bi][swz_u16(row, kc)]);
      acc[n] = mfma16(ah, bh, acc[n]);
      acc[n] = mfma16(ah, bl, acc[n]);
      acc[n] = mfma16(al, bh, acc[n]);
    }
  };

  constexpr int NT = kH / 32;   // 24
  STAGE(0, 0);
  int cur = 0;
  for (int t = 0; t < NT - 1; ++t) {
    STAGE(cur ^ 1, (t + 1) * 32);
    asm volatile("s_waitcnt vmcnt(6)" ::: "memory");
    __builtin_amdgcn_s_barrier();
    __builtin_amdgcn_sched_barrier(0);
    COMPUTE(cur);
    __builtin_amdgcn_sched_barrier(0);
    __builtin_amdgcn_s_barrier();
    cur ^= 1;
  }
  asm volatile("s_waitcnt vmcnt(0)" ::: "memory");
  __builtin_amdgcn_s_barrier();
  __builtin_amdgcn_sched_barrier(0);
  COMPUTE(cur);

  // epilogue: frag n -> gate n>>1, unit-half n&1. Per lane: all 4 gates of unit u.
  const int rq = (lane >> 4) * 4;
#pragma unroll
  for (int h = 0; h < 2; ++h) {
    int u = u0 + h * 16 + cl;
#pragma unroll
    for (int q = 0; q < 4; ++q) {
      int r = bm + wid * 16 + rq + q;
      size_t gb = (size_t)r * kG;
      float gi = acc[0 + h][q] + gxt[gb + u];
      float gf = acc[2 + h][q] + gxt[gb + kH + u];
      float gg = acc[4 + h][q] + gxt[gb + 2 * kH + u];
      float go = acc[6 + h][q] + gxt[gb + 3 * kH + u];
      float i_ = sigm(gi), f_ = sigm(gf), g_ = tanhf(gg), o_ = sigm(go);
      size_t co = (size_t)r * kH + u;
      float cn = fmaf(f_, cbuf[co], i_ * g_);
      cbuf[co] = cn;
      float hv = o_ * tanhf(cn);
      u16 hh = f2bf(hv);
      Ohi[co] = hh;
      Olo[co] = f2bf(hv - bf2f(hh));
    }
  }
}

// ---------------- t=0 gates (h0 = 0, c0 = 0) ----------------
__global__ __launch_bounds__(256) void lstm_t0(const float* __restrict__ gxt,
                                               float* __restrict__ cbuf,
                                               u16* __restrict__ Ohi,
                                               u16* __restrict__ Olo) {
  int idx = blockIdx.x * 256 + threadIdx.x;   // 512*768
  int b = idx / kH, u = idx % kH;
  size_t base = (size_t)b * kG;
  float gi = gxt[base + u];
  float gg = gxt[base + 2 * kH + u];
  float go = gxt[base + 3 * kH + u];
  float i_ = sigm(gi), g_ = tanhf(gg), o_ = sigm(go);
  float cn = i_ * g_;
  cbuf[idx] = cn;
  float hv = o_ * tanhf(cn);
  u16 hh = f2bf(hv);
  Ohi[idx] = hh;
  Olo[idx] = f2bf(hv - bf2f(hh));
}

}  // namespace

extern "C" void kernel_launch(void* const* d_in, const int* in_sizes, int n_in,
                              void* d_out, int out_size, void* d_ws, size_t ws_size,
                              hipStream_t stream) {
  const float* xpos  = (const float*)d_in[0];
  const float* fc0_w = (const float*)d_in[1];
  const float* fc0_b = (const float*)d_in[2];
  const float* w_ih  = (const float*)d_in[3];
  const float* w_hh  = (const float*)d_in[4];
  const float* b_ih  = (const float*)d_in[5];
  const float* b_hh  = (const float*)d_in[6];
  const float* fc1_w = (const float*)d_in[7];
  const float* fc1_b = (const float*)d_in[8];
  float* out = (float*)d_out;

  // ---- workspace (101,449,728 B total; proven available) ----
  // gx region [0, 62.9MB) aliases: Xt hi/lo [0, 15.7MB); fc1w split
  // [16.8MB, 40.4MB); fc1 partials [40.4MB, 59.2MB)
  char* W = (char*)d_ws;
  float* gx      = (float*)W;                     // 5120*3072 f32
  u16* Xthi      = (u16*)W;                       // 5120*768
  u16* Xtlo      = Xthi + (size_t)kTB * kH;
  u16* fc1whi    = (u16*)(W + 16777216);          // 768*7680
  u16* fc1wlo    = fc1whi + (size_t)kH * kH * kW;
  float* fc1part = (float*)(W + 40370176);        // 12 * 512*768 f32
  u16* Yhi       = (u16*)(W + 62914560);          // 10*512*768
  u16* Ylo       = Yhi + (size_t)kTB * kH;
  float* cbuf    = (float*)(W + 78643200);        // 512*768
  u16* wihhi     = (u16*)(W + 80216064);          // 3072*768
  u16* wihlo     = wihhi + (size_t)kG * kH;
  u16* whhhi     = (u16*)(W + 89653248);
  u16* whhlo     = whhhi + (size_t)kG * kH;
  u16* fc0whi    = (u16*)(W + 99090432);          // 768*768
  u16* fc0wlo    = fc0whi + (size_t)kH * kH;

  dim3 blk(256);

  transpose_split<<<3840, blk, 0, stream>>>(xpos, Xthi, Xtlo);
  split4<<<576, blk, 0, stream>>>(fc0_w, fc0whi, fc0wlo);

  // fc0: Y = Xt @ fc0_w^T + b   (5120 x 768 x 768), split output
  gemm_bf3<128, 1><<<dim3(6, 40), blk, 0, stream>>>(
      Xthi, Xtlo, fc0whi, fc0wlo, fc0_b, nullptr, nullptr, Yhi, Ylo,
      kTB, kH, kH, kH);

  for (int l = 0; l < kL; ++l) {
    split2<<<4608, blk, 0, stream>>>(w_ih + (size_t)l * kG * kH,
                                     w_hh + (size_t)l * kG * kH,
                                     wihhi, wihlo, whhhi, whhlo);

    // gx = Y @ wih^T + b_ih + b_hh   (5120 x 3072 x 768)
    gemm_bf3<128, 2><<<dim3(24, 40), blk, 0, stream>>>(
        Yhi, Ylo, wihhi, wihlo, b_ih + (size_t)l * kG, b_hh + (size_t)l * kG,
        gx, nullptr, nullptr, kTB, kG, kH, kH);

    lstm_t0<<<1536, blk, 0, stream>>>(gx, cbuf, Yhi, Ylo);

    for (int t = 1; t < kW; ++t) {
      lstm_step<<<dim3(24, 8), blk, 0, stream>>>(
          Yhi + (size_t)(t - 1) * kB * kH, Ylo + (size_t)(t - 1) * kB * kH,
          whhhi, whhlo, gx + (size_t)t * kB * kG, cbuf,
          Yhi + (size_t)t * kB * kH, Ylo + (size_t)t * kB * kH);
    }
  }

  // fc1: split weight, pack xx, split-K GEMM into partials, reduce (+bias)
  split4<<<5760, blk, 0, stream>>>(fc1_w, fc1whi, fc1wlo);
  pack_sp<<<1920, blk, 0, stream>>>(Yhi, Ylo, Xthi, Xtlo);
  gemm_bf3<64, 3><<<dim3(6, 8, kFC1_SPLIT), blk, 0, stream>>>(
      Xthi, Xtlo, fc1whi, fc1wlo, nullptr, nullptr, fc1part, nullptr, nullptr,
      kB, kH, kW * kH, kW * kH / kFC1_SPLIT);
  fc1_reduce<<<1536, blk, 0, stream>>>(fc1part, fc1_b, out);
}

// Round 10
// 3031.584 us; speedup vs baseline: 1.3664x; 1.1887x over previous
//
#include <hip/hip_runtime.h>

namespace {

using u16 = unsigned short;
typedef short s16x8 __attribute__((ext_vector_type(8)));
typedef float f32x4 __attribute__((ext_vector_type(4)));
typedef u16 u16x4 __attribute__((ext_vector_type(4)));

constexpr int kH  = 768;
constexpr int kW  = 10;
constexpr int kL  = 10;
constexpr int kB  = 512;
constexpr int kG  = 3072;      // 4*H
constexpr int kTB = 5120;      // W*B
constexpr int kFC1_SPLIT = 12; // fc1 split-K chunks (Ksub = 640)

// ---- bf16 helpers (RNE) ----
__device__ __forceinline__ u16 f2bf(float x) {
  unsigned u = __float_as_uint(x);
  unsigned r = (u + 0x7fffu + ((u >> 16) & 1u)) >> 16;
  return (u16)r;
}
__device__ __forceinline__ float bf2f(u16 h) {
  return __uint_as_float(((unsigned)h) << 16);
}
// packed RNE f32x2 -> bf16x2 (lo = a, hi = b)
__device__ __forceinline__ unsigned cvtpk(float a, float b) {
  unsigned r;
  asm("v_cvt_pk_bf16_f32 %0, %1, %2" : "=v"(r) : "v"(a), "v"(b));
  return r;
}

// ---- async global->LDS, 16B/lane, LDS dst wave-uniform base + lane*16 ----
__device__ __forceinline__ void gl2lds(const void* g, void* l) {
  __builtin_amdgcn_global_load_lds(
      (const __attribute__((address_space(1))) void*)g,
      (__attribute__((address_space(3))) void*)l, 16, 0, 0);
}

__device__ __forceinline__ f32x4 mfma16(s16x8 a, s16x8 b, f32x4 c) {
  return __builtin_amdgcn_mfma_f32_16x16x32_bf16(a, b, c, 0, 0, 0);
}

__device__ __forceinline__ float sigm(float x) { return 1.f / (1.f + __expf(-x)); }

// ---- LDS tile swizzle (verified: SQ_LDS_BANK_CONFLICT 7.37M -> 0) ----
__device__ __forceinline__ int swz_u16(int row, int kc) {
  return row * 32 + ((kc ^ ((row >> 1) & 3)) << 3);
}

// ---------------- fp32 -> bf16 hi/lo split (4 elems/thread) ----------------
__device__ __forceinline__ void split_store(const float4 v, u16* hi, u16* lo, int idx) {
  u16x4 h, l;
  h[0] = f2bf(v.x); l[0] = f2bf(v.x - bf2f(h[0]));
  h[1] = f2bf(v.y); l[1] = f2bf(v.y - bf2f(h[1]));
  h[2] = f2bf(v.z); l[2] = f2bf(v.z - bf2f(h[2]));
  h[3] = f2bf(v.w); l[3] = f2bf(v.w - bf2f(h[3]));
  reinterpret_cast<u16x4*>(hi)[idx] = h;
  reinterpret_cast<u16x4*>(lo)[idx] = l;
}

__global__ __launch_bounds__(256) void split4(const float* __restrict__ in,
                                              u16* __restrict__ hi,
                                              u16* __restrict__ lo) {
  int idx = blockIdx.x * 256 + threadIdx.x;
  split_store(reinterpret_cast<const float4*>(in)[idx], hi, lo, idx);
}

// ---------------- transpose (B,W,H)->(W,B,H) + split ----------------
__global__ __launch_bounds__(256) void transpose_split(const float* __restrict__ src,
                                                       u16* __restrict__ hi,
                                                       u16* __restrict__ lo) {
  int idx = blockIdx.x * 256 + threadIdx.x;   // float4 units, 5120*192 total
  int h4 = idx % 192;
  int rest = idx / 192;
  int b = rest % kB;
  int t = rest / kB;
  float4 v = reinterpret_cast<const float4*>(src)[((size_t)b * kW + t) * 192 + h4];
  split_store(v, hi, lo, (int)(((size_t)t * kB + b) * 192 + h4));
}

// ---------------- pack (W,B,H)->(B,W*H), bf16 pairs ----------------
__global__ __launch_bounds__(256) void pack_sp(const u16* __restrict__ Yhi,
                                               const u16* __restrict__ Ylo,
                                               u16* __restrict__ Xhi,
                                               u16* __restrict__ Xlo) {
  int idx = blockIdx.x * 256 + threadIdx.x;   // uint4 units (8 u16)
  int h8 = idx % 96;
  int rest = idx / 96;
  int w = rest % kW;
  int b = rest / kW;
  size_t s = ((size_t)w * kB + b) * 96 + h8;
  size_t d = ((size_t)b * kW + w) * 96 + h8;
  reinterpret_cast<uint4*>(Xhi)[d] = reinterpret_cast<const uint4*>(Yhi)[s];
  reinterpret_cast<uint4*>(Xlo)[d] = reinterpret_cast<const uint4*>(Ylo)[s];
}

// ======== bf16x3 GEMM: dbuf + counted vmcnt + raw barriers (round-9) ========
// EPI: 1 split hi/lo+bias1; 3 fp32 split-K partials (blockIdx.z plane, no bias).
template <int BM, int EPI>
__global__ __launch_bounds__(256) void gemm_bf3(
    const u16* __restrict__ Ahi, const u16* __restrict__ Alo,
    const u16* __restrict__ Bhi, const u16* __restrict__ Blo,
    const float* __restrict__ bias1,
    float* __restrict__ Cf, u16* __restrict__ Chi, u16* __restrict__ Clo,
    int M, int N, int K, int Ksub) {
  constexpr int MR = BM / 64;
  constexpr int WR = BM / 4;
  __shared__ u16 sAh[2][BM * 32], sAl[2][BM * 32];
  __shared__ u16 sBh[2][128 * 32], sBl[2][128 * 32];
  const int tid = threadIdx.x;
  const int wid = tid >> 6;
  const int lane = tid & 63;
  const int bm = blockIdx.y * BM;
  const int bn = blockIdx.x * 128;
  const int kbeg = blockIdx.z * Ksub;

  f32x4 acc[MR][8];
#pragma unroll
  for (int m = 0; m < MR; ++m)
#pragma unroll
    for (int n = 0; n < 8; ++n) acc[m][n] = {0.f, 0.f, 0.f, 0.f};

  const int kc = lane >> 4;
  const int cl = lane & 15;
  const int srow = lane >> 2;
  const int scol = (((lane & 3) ^ ((srow >> 1) & 3)) << 3);

  auto STAGE = [&](int bi, int k0) {
#pragma unroll
    for (int c = 0; c < MR; ++c) {
      int g16 = (wid * MR + c) * 16;
      size_t goff = (size_t)(bm + g16 + srow) * K + k0 + scol;
      gl2lds(Ahi + goff, &sAh[bi][g16 * 32]);
      gl2lds(Alo + goff, &sAl[bi][g16 * 32]);
    }
#pragma unroll
    for (int c = 0; c < 2; ++c) {
      int g16 = (wid * 2 + c) * 16;
      size_t goff = (size_t)(bn + g16 + srow) * K + k0 + scol;
      gl2lds(Bhi + goff, &sBh[bi][g16 * 32]);
      gl2lds(Blo + goff, &sBl[bi][g16 * 32]);
    }
  };

  auto COMPUTE = [&](int bi) {
    s16x8 ah[MR], al[MR];
#pragma unroll
    for (int m = 0; m < MR; ++m) {
      int row = wid * WR + m * 16 + cl;
      ah[m] = *reinterpret_cast<const s16x8*>(&sAh[bi][swz_u16(row, kc)]);
      al[m] = *reinterpret_cast<const s16x8*>(&sAl[bi][swz_u16(row, kc)]);
    }
#pragma unroll
    for (int n = 0; n < 8; ++n) {
      int row = n * 16 + cl;
      s16x8 bh = *reinterpret_cast<const s16x8*>(&sBh[bi][swz_u16(row, kc)]);
      s16x8 bl = *reinterpret_cast<const s16x8*>(&sBl[bi][swz_u16(row, kc)]);
#pragma unroll
      for (int m = 0; m < MR; ++m) acc[m][n] = mfma16(ah[m], bh, acc[m][n]);
#pragma unroll
      for (int m = 0; m < MR; ++m) acc[m][n] = mfma16(ah[m], bl, acc[m][n]);
#pragma unroll
      for (int m = 0; m < MR; ++m) acc[m][n] = mfma16(al[m], bh, acc[m][n]);
    }
  };

  const int NT = Ksub / 32;
  STAGE(0, kbeg);
  int cur = 0;
  for (int t = 0; t < NT - 1; ++t) {
    STAGE(cur ^ 1, kbeg + (t + 1) * 32);
    if constexpr (MR == 2) asm volatile("s_waitcnt vmcnt(8)" ::: "memory");
    else                   asm volatile("s_waitcnt vmcnt(6)" ::: "memory");
    __builtin_amdgcn_s_barrier();
    __builtin_amdgcn_sched_barrier(0);
    COMPUTE(cur);
    __builtin_amdgcn_sched_barrier(0);
    __builtin_amdgcn_s_barrier();
    cur ^= 1;
  }
  asm volatile("s_waitcnt vmcnt(0)" ::: "memory");
  __builtin_amdgcn_s_barrier();
  __builtin_amdgcn_sched_barrier(0);
  COMPUTE(cur);

  const int rq = (lane >> 4) * 4;
#pragma unroll
  for (int m = 0; m < MR; ++m) {
#pragma unroll
    for (int n = 0; n < 8; ++n) {
      int col = bn + n * 16 + cl;
      float badd = (EPI != 3 && bias1) ? bias1[col] : 0.f;
#pragma unroll
      for (int q = 0; q < 4; ++q) {
        int row = bm + wid * WR + m * 16 + rq + q;
        float v = acc[m][n][q] + badd;
        if (EPI == 1) {
          size_t off = (size_t)row * N + col;
          u16 h = f2bf(v);
          Chi[off] = h;
          Clo[off] = f2bf(v - bf2f(h));
        } else {
          size_t off = ((size_t)blockIdx.z * M + row) * N + col;
          Cf[off] = v;
        }
      }
    }
  }
}

// ---- fc1 partial reduce: out = bias + sum_z part[z] ----
__global__ __launch_bounds__(256) void fc1_reduce(const float* __restrict__ part,
                                                  const float* __restrict__ bias,
                                                  float* __restrict__ out) {
  int idx = blockIdx.x * 256 + threadIdx.x;   // 512*768
  float s = bias[idx % kH];
#pragma unroll
  for (int z = 0; z < kFC1_SPLIT; ++z) s += part[(size_t)z * kB * kH + idx];
  out[idx] = s;
}

// ======== diagonal-wavefront fused LSTM cell ========
// Cells (l, t=d-l) on anti-diagonal d are independent. One block computes a
// 64(batch) x 128(4 gates x 32 units) tile of cell (l,t)'s pre-activations by
// a fused K-loop: steps 0..23 over (h_in, wih_l), 24..47 over (h_prev, whh_l),
// accumulating into one acc; then gates + c/h update in the epilogue.
// A (h, bf16 hi/lo) staged via gl2lds w/ pre-swizzled source; B (weights,
// fp32 in HBM) reg-staged: 4x float4 loads -> cvt_pk hi/lo -> swizzled
// ds_write_b128 (issue-early / write-late; vmcnt(2) retires {prev A, new B}).
// grid = (24, 8, ncells).
__global__ __launch_bounds__(256) void diag_cell(
    int lmin, int d,
    u16* __restrict__ fc0Yhi, u16* __restrict__ fc0Ylo,       // in (l==0) / out (l==9)
    const u16* __restrict__ pHhi, const u16* __restrict__ pHlo,
    u16* __restrict__ cHhi, u16* __restrict__ cHlo,
    float* __restrict__ cbuf,
    const float* __restrict__ w_ih_all, const float* __restrict__ w_hh_all,
    const float* __restrict__ b_ih_all, const float* __restrict__ b_hh_all) {
  constexpr int SZ = kB * kH;
  __shared__ u16 sAh[2][64 * 32], sAl[2][64 * 32];
  __shared__ u16 sBh[2][128 * 32], sBl[2][128 * 32];

  const int l = lmin + (int)blockIdx.z;
  const int t = d - l;
  const int u0 = blockIdx.x * 32;
  const int bm = blockIdx.y * 64;

  const u16* hin_hi = (l == 0) ? fc0Yhi + (size_t)t * SZ : pHhi + (size_t)(l - 1) * SZ;
  const u16* hin_lo = (l == 0) ? fc0Ylo + (size_t)t * SZ : pHlo + (size_t)(l - 1) * SZ;
  const u16* hpr_hi = pHhi + (size_t)l * SZ;
  const u16* hpr_lo = pHlo + (size_t)l * SZ;
  const float* wih = w_ih_all + (size_t)l * kG * kH;
  const float* whh = w_hh_all + (size_t)l * kG * kH;
  const float* bih = b_ih_all + (size_t)l * kG;
  const float* bhh = b_hh_all + (size_t)l * kG;

  const int tid = threadIdx.x;
  const int wid = tid >> 6;
  const int lane = tid & 63;
  const int kc = lane >> 4;
  const int cl = lane & 15;
  const int srow = lane >> 2;
  const int scol = (((lane & 3) ^ ((srow >> 1) & 3)) << 3);

  // B reg-staging mapping: thread -> (tile row, k half)
  const int br = tid & 127;                 // B tile row (slab*32 + j)
  const int kh = tid >> 7;                  // 16-col half
  const size_t wrowoff = (size_t)((br >> 5) * kH + u0 + (br & 31)) * kH;

  f32x4 acc[8];
#pragma unroll
  for (int n = 0; n < 8; ++n) acc[n] = {0.f, 0.f, 0.f, 0.f};

  const int NT = (t == 0) ? 24 : 48;
  float4 bq0, bq1, bq2, bq3;

  auto ISSUE = [&](int s, int bi) {
    int ph = s >= 24;
    int ks = s * 32 - ph * 768;
    const float* bsrc = (ph ? whh : wih) + wrowoff + ks + kh * 16;
    bq0 = reinterpret_cast<const float4*>(bsrc)[0];
    bq1 = reinterpret_cast<const float4*>(bsrc)[1];
    bq2 = reinterpret_cast<const float4*>(bsrc)[2];
    bq3 = reinterpret_cast<const float4*>(bsrc)[3];
    __builtin_amdgcn_sched_barrier(0);      // B loads issue before gl2lds
    const u16* Ah = ph ? hpr_hi : hin_hi;
    const u16* Al = ph ? hpr_lo : hin_lo;
    int g16 = wid * 16;
    size_t goff = (size_t)(bm + g16 + srow) * kH + ks + scol;
    gl2lds(Ah + goff, &sAh[bi][g16 * 32]);
    gl2lds(Al + goff, &sAl[bi][g16 * 32]);
  };

  auto WRITEB = [&](int bi) {
#pragma unroll
    for (int half = 0; half < 2; ++half) {
      float4 a = half ? bq2 : bq0;
      float4 b = half ? bq3 : bq1;
      unsigned h0 = cvtpk(a.x, a.y), h1 = cvtpk(a.z, a.w);
      unsigned h2 = cvtpk(b.x, b.y), h3 = cvtpk(b.z, b.w);
      float r0 = a.x - __uint_as_float(h0 << 16);
      float r1 = a.y - __uint_as_float(h0 & 0xffff0000u);
      float r2 = a.z - __uint_as_float(h1 << 16);
      float r3 = a.w - __uint_as_float(h1 & 0xffff0000u);
      float r4 = b.x - __uint_as_float(h2 << 16);
      float r5 = b.y - __uint_as_float(h2 & 0xffff0000u);
      float r6 = b.z - __uint_as_float(h3 << 16);
      float r7 = b.w - __uint_as_float(h3 & 0xffff0000u);
      unsigned l0 = cvtpk(r0, r1), l1 = cvtpk(r2, r3);
      unsigned l2 = cvtpk(r4, r5), l3 = cvtpk(r6, r7);
      int ad = swz_u16(br, kh * 2 + half);
      reinterpret_cast<uint4&>(sBh[bi][ad]) = uint4{h0, h1, h2, h3};
      reinterpret_cast<uint4&>(sBl[bi][ad]) = uint4{l0, l1, l2, l3};
    }
  };

  auto COMPUTE = [&](int bi) {
    int arow = wid * 16 + cl;
    s16x8 ah = *reinterpret_cast<const s16x8*>(&sAh[bi][swz_u16(arow, kc)]);
    s16x8 al = *reinterpret_cast<const s16x8*>(&sAl[bi][swz_u16(arow, kc)]);
#pragma unroll
    for (int n = 0; n < 8; ++n) {
      int row = n * 16 + cl;
      s16x8 bh = *reinterpret_cast<const s16x8*>(&sBh[bi][swz_u16(row, kc)]);
      s16x8 bl = *reinterpret_cast<const s16x8*>(&sBl[bi][swz_u16(row, kc)]);
      acc[n] = mfma16(ah, bh, acc[n]);
      acc[n] = mfma16(ah, bl, acc[n]);
      acc[n] = mfma16(al, bh, acc[n]);
    }
  };

  // prologue: stage k-step 0 into buf 0
  ISSUE(0, 0);
  asm volatile("s_waitcnt vmcnt(2)" ::: "memory");   // B f4s landed
  WRITEB(0);
  asm volatile("s_waitcnt lgkmcnt(0)" ::: "memory");
  __builtin_amdgcn_s_barrier();

  int cur = 0;
  for (int s = 0; s < NT - 1; ++s) {
    ISSUE(s + 1, cur ^ 1);
    // retires: A-gl2lds(s) [oldest 2] + B-f4(s+1) [next 4]; leaves A(s+1)
    asm volatile("s_waitcnt vmcnt(2)" ::: "memory");
    __builtin_amdgcn_s_barrier();
    __builtin_amdgcn_sched_barrier(0);
    WRITEB(cur ^ 1);            // write next-buf B (drains under MFMAs)
    COMPUTE(cur);
    __builtin_amdgcn_sched_barrier(0);
    asm volatile("s_waitcnt lgkmcnt(0)" ::: "memory");
    __builtin_amdgcn_s_barrier();
    cur ^= 1;
  }
  asm volatile("s_waitcnt vmcnt(0)" ::: "memory");
  __builtin_amdgcn_s_barrier();
  __builtin_amdgcn_sched_barrier(0);
  COMPUTE(cur);

  // epilogue: frag n -> gate n>>1, unit-half n&1; gates + c/h update
  const int rq = (lane >> 4) * 4;
#pragma unroll
  for (int h = 0; h < 2; ++h) {
    int u = u0 + h * 16 + cl;
    float b_i = bih[u] + bhh[u];
    float b_f = bih[kH + u] + bhh[kH + u];
    float b_g = bih[2 * kH + u] + bhh[2 * kH + u];
    float b_o = bih[3 * kH + u] + bhh[3 * kH + u];
#pragma unroll
    for (int q = 0; q < 4; ++q) {
      int r = bm + wid * 16 + rq + q;
      float gi = acc[0 + h][q] + b_i;
      float gf = acc[2 + h][q] + b_f;
      float gg = acc[4 + h][q] + b_g;
      float go = acc[6 + h][q] + b_o;
      float i_ = sigm(gi), f_ = sigm(gf), g_ = tanhf(gg), o_ = sigm(go);
      size_t co = (size_t)l * SZ + (size_t)r * kH + u;
      float cp = (t == 0) ? 0.f : cbuf[co];
      float cn = fmaf(f_, cp, i_ * g_);
      cbuf[co] = cn;
      float hv = o_ * tanhf(cn);
      u16 hh_ = f2bf(hv);
      u16 hl_ = f2bf(hv - bf2f(hh_));
      cHhi[co] = hh_;
      cHlo[co] = hl_;
      if (l == kL - 1) {          // final layer: also write Ylast (fc0Y overlay)
        size_t yo = (size_t)t * SZ + (size_t)r * kH + u;
        fc0Yhi[yo] = hh_;
        fc0Ylo[yo] = hl_;
      }
    }
  }
}

}  // namespace

extern "C" void kernel_launch(void* const* d_in, const int* in_sizes, int n_in,
                              void* d_out, int out_size, void* d_ws, size_t ws_size,
                              hipStream_t stream) {
  const float* xpos  = (const float*)d_in[0];
  const float* fc0_w = (const float*)d_in[1];
  const float* fc0_b = (const float*)d_in[2];
  const float* w_ih  = (const float*)d_in[3];
  const float* w_hh  = (const float*)d_in[4];
  const float* b_ih  = (const float*)d_in[5];
  const float* b_hh  = (const float*)d_in[6];
  const float* fc1_w = (const float*)d_in[7];
  const float* fc1_b = (const float*)d_in[8];
  float* out = (float*)d_out;

  // ---- workspace (peak 81.8 MB; 101.4 MB proven available) ----
  // 0        fc0Yhi [7.86M]  (fc0 out; Ylast overlay from d>=9)
  // 7864320  fc0Ylo [7.86M]
  // 15728640 slot0 hi [7.86M]  | overlays: Xthi (pre-d0), fc1whi (post-d18)
  // 23592960 slot0 lo [7.86M]  | overlays: Xtlo, fc1w...
  // 31457280 slot1 hi [7.86M]  | overlay: fc1wlo tail
  // 39321600 slot1 lo [7.86M]  | overlay: XPhi (packed fc1 input)
  // 47185920 cbuf [15.73M fp32]| overlay: XPlo (post-d18)
  // 62914560 fc0w split [2.4M] | overlay: fc1part [18.9M]
  char* W = (char*)d_ws;
  u16* fc0Yhi = (u16*)W;
  u16* fc0Ylo = (u16*)(W + 7864320);
  u16* slotHi[2] = {(u16*)(W + 15728640), (u16*)(W + 31457280)};
  u16* slotLo[2] = {(u16*)(W + 23592960), (u16*)(W + 39321600)};
  float* cbuf = (float*)(W + 47185920);
  u16* Xthi   = (u16*)(W + 15728640);
  u16* Xtlo   = (u16*)(W + 23592960);
  u16* fc0whi = (u16*)(W + 62914560);
  u16* fc0wlo = fc0whi + (size_t)kH * kH;
  u16* fc1whi = (u16*)(W + 15728640);
  u16* fc1wlo = (u16*)(W + 27525120);
  u16* XPhi   = (u16*)(W + 39321600);
  u16* XPlo   = (u16*)(W + 47185920);
  float* fc1part = (float*)(W + 62914560);

  dim3 blk(256);

  transpose_split<<<3840, blk, 0, stream>>>(xpos, Xthi, Xtlo);
  split4<<<576, blk, 0, stream>>>(fc0_w, fc0whi, fc0wlo);

  // fc0: fc0Y = Xt @ fc0_w^T + b   (5120 x 768 x 768), split hi/lo out
  gemm_bf3<128, 1><<<dim3(6, 40), blk, 0, stream>>>(
      Xthi, Xtlo, fc0whi, fc0wlo, fc0_b, nullptr, fc0Yhi, fc0Ylo,
      kTB, kH, kH, kH);

  // anti-diagonal wavefront over the 10x10 (layer, time) cell grid
  for (int d = 0; d <= 18; ++d) {
    int lmin = d > 9 ? d - 9 : 0;
    int lmax = d < 9 ? d : 9;
    int nc = lmax - lmin + 1;
    int cs = d & 1, ps = cs ^ 1;
    diag_cell<<<dim3(24, 8, nc), blk, 0, stream>>>(
        lmin, d, fc0Yhi, fc0Ylo, slotHi[ps], slotLo[ps], slotHi[cs], slotLo[cs],
        cbuf, w_ih, w_hh, b_ih, b_hh);
  }

  // fc1: split weight, pack xx, split-K GEMM into partials, reduce (+bias)
  split4<<<5760, blk, 0, stream>>>(fc1_w, fc1whi, fc1wlo);
  pack_sp<<<1920, blk, 0, stream>>>(fc0Yhi, fc0Ylo, XPhi, XPlo);
  gemm_bf3<64, 3><<<dim3(6, 8, kFC1_SPLIT), blk, 0, stream>>>(
      XPhi, XPlo, fc1whi, fc1wlo, nullptr, fc1part, nullptr, nullptr,
      kB, kH, kW * kH, kW * kH / kFC1_SPLIT);
  fc1_reduce<<<1536, blk, 0, stream>>>(fc1part, fc1_b, out);
}